// Round 1
// baseline (6715.184 us; speedup 1.0000x reference)
//
#include <hip/hip_runtime.h>
#include <math.h>

constexpr int FDIM = 128;   // IN == HID
constexpr int ODIM = 64;    // NC

// ---------------- column stats (deterministic two-stage) ----------------
template<int C>
__global__ void k_colstats(const float* __restrict__ X, int N, float* __restrict__ partial) {
    const int c = threadIdx.x;          // blockDim.x == C
    const int nb = gridDim.x;
    const int rows_per = (N + nb - 1) / nb;
    const int r0 = blockIdx.x * rows_per;
    const int r1 = min(N, r0 + rows_per);
    float s = 0.f, ss = 0.f;
    for (int r = r0; r < r1; ++r) {
        float v = X[(size_t)r * C + c];
        s += v;
        ss += v * v;
    }
    partial[(size_t)blockIdx.x * (2 * C) + c]     = s;
    partial[(size_t)blockIdx.x * (2 * C) + C + c] = ss;
}

template<int C>
__global__ void k_colstats_fin(const float* __restrict__ partial, int nb, int N,
                               const float* __restrict__ gamma, const float* __restrict__ beta,
                               float* __restrict__ scale, float* __restrict__ shift) {
    const int c = threadIdx.x;          // blockDim.x == C
    float s = 0.f, ss = 0.f;
    for (int b = 0; b < nb; ++b) {
        s  += partial[(size_t)b * (2 * C) + c];
        ss += partial[(size_t)b * (2 * C) + C + c];
    }
    const float mu  = s / (float)N;
    const float var = ss / (float)N - mu * mu;
    const float sc  = gamma[c] * rsqrtf(var + 1e-5f);
    scale[c] = sc;
    shift[c] = beta[c] - mu * sc;
}

// ---------------- degree ----------------
__global__ void k_deg(const int* __restrict__ dst, int E, unsigned* __restrict__ deg) {
    int i = blockIdx.x * blockDim.x + threadIdx.x;
    const int stride = gridDim.x * blockDim.x;
    for (; i < E; i += stride) atomicAdd(&deg[dst[i]], 1u);
}

__global__ void k_rinv(const unsigned* __restrict__ deg, float* __restrict__ rinv, int n) {
    int i = blockIdx.x * blockDim.x + threadIdx.x;
    if (i < n) rinv[i] = 1.0f / ((float)deg[i] + 1.0f);
}

// ---------------- BN1 apply + init 3 AGG copies ----------------
__global__ void k_bn_init(const float* __restrict__ x, const float* __restrict__ scale,
                          const float* __restrict__ shift, float* __restrict__ xn,
                          float* __restrict__ agg, size_t n4 /* = N*32 float4s */) {
    const float4* x4  = (const float4*)x;
    const float4* sc4 = (const float4*)scale;
    const float4* sh4 = (const float4*)shift;
    float4* xn4  = (float4*)xn;
    float4* agg4 = (float4*)agg;
    for (size_t i = (size_t)blockIdx.x * blockDim.x + threadIdx.x; i < n4;
         i += (size_t)gridDim.x * blockDim.x) {
        const int c = (int)(i & 31);
        float4 v = x4[i], sc = sc4[c], sh = sh4[c], o;
        o.x = fmaf(v.x, sc.x, sh.x);
        o.y = fmaf(v.y, sc.y, sh.y);
        o.z = fmaf(v.z, sc.z, sh.z);
        o.w = fmaf(v.w, sc.w, sh.w);
        xn4[i] = o;
        agg4[i] = o;
        agg4[i + n4] = o;
        agg4[i + 2 * n4] = o;
    }
}

// ---------------- BN apply in place ----------------
__global__ void k_bn_apply(float* __restrict__ X, const float* __restrict__ scale,
                           const float* __restrict__ shift, size_t n4) {
    float4* x4 = (float4*)X;
    const float4* sc4 = (const float4*)scale;
    const float4* sh4 = (const float4*)shift;
    for (size_t i = (size_t)blockIdx.x * blockDim.x + threadIdx.x; i < n4;
         i += (size_t)gridDim.x * blockDim.x) {
        const int c = (int)(i & 31);
        float4 v = x4[i], sc = sc4[c], sh = sh4[c];
        v.x = fmaf(v.x, sc.x, sh.x);
        v.y = fmaf(v.y, sc.y, sh.y);
        v.z = fmaf(v.z, sc.z, sh.z);
        v.w = fmaf(v.w, sc.w, sh.w);
        x4[i] = v;
    }
}

// ---------------- edge scatter-add: A[dst] += X[src], C floats per edge ----------------
template<int C>
__global__ void k_scatter(const int* __restrict__ src, const int* __restrict__ dst,
                          const float* __restrict__ X, float* __restrict__ A, int E) {
    constexpr int TPE = C / 4;          // threads per edge (float4 granularity)
    const size_t total = (size_t)E * TPE;
    const size_t stride = (size_t)gridDim.x * blockDim.x;
    for (size_t t = (size_t)blockIdx.x * blockDim.x + threadIdx.x; t < total; t += stride) {
        const int e = (int)(t / TPE);
        const int j = (int)(t % TPE);
        const int u = src[e];
        const int v = dst[e];
        const float4 val = ((const float4*)(X + (size_t)u * C))[j];
        float* p = A + (size_t)v * C + 4 * j;
        atomicAdd(p + 0, val.x);
        atomicAdd(p + 1, val.y);
        atomicAdd(p + 2, val.z);
        atomicAdd(p + 3, val.w);
    }
}

// ---------------- GEMM1: H = relu( sum_g (AGG_g * rinv_g) @ W_g + sum_g b_g ), 384->128 ----------------
__global__ __launch_bounds__(256) void k_gemm1(
    const float* __restrict__ AGG, const float* __restrict__ rinv,
    const float* __restrict__ W1, const float* __restrict__ W2, const float* __restrict__ W3,
    const float* __restrict__ b1, const float* __restrict__ b2, const float* __restrict__ b3,
    float* __restrict__ H, int N) {
    __shared__ float At[16][64];
    __shared__ float Bt[16][128];
    const int t = threadIdx.x;
    const int row0 = blockIdx.x * 64;
    const int c0 = (t & 31) * 4;     // 0..124
    const int r0 = (t >> 5) * 8;     // 0..56
    float acc[8][4];
    #pragma unroll
    for (int r = 0; r < 8; ++r)
        #pragma unroll
        for (int c = 0; c < 4; ++c) acc[r][c] = 0.f;

    for (int kb = 0; kb < 24; ++kb) {      // K = 384, tiles of 16
        const int kglob0 = kb * 16;
        const int g = kglob0 >> 7;          // which graph block
        const int kloc0 = kglob0 & 127;
        // load At[kk][r] = AGG_g[row, kloc0+kk] * rinv_g[row]
        {
            const int kk = t & 15;
            const int rb = t >> 4;          // 0..15
            const float* Ag = AGG + (size_t)g * N * FDIM;
            const float* rv = rinv + (size_t)g * N;
            #pragma unroll
            for (int it = 0; it < 4; ++it) {
                const int r = rb + it * 16;
                const int row = row0 + r;
                float v = 0.f;
                if (row < N) v = Ag[(size_t)row * FDIM + kloc0 + kk] * rv[row];
                At[kk][r] = v;
            }
        }
        // load Bt[kk][n] = W_g[kloc0+kk, n]
        {
            const int n = t & 127;
            const int kkb = t >> 7;         // 0..1
            const float* Wg = (g == 0) ? W1 : (g == 1) ? W2 : W3;
            #pragma unroll
            for (int it = 0; it < 8; ++it) {
                const int kk = kkb + it * 2;
                Bt[kk][n] = Wg[(size_t)(kloc0 + kk) * 128 + n];
            }
        }
        __syncthreads();
        #pragma unroll
        for (int kk = 0; kk < 16; ++kk) {
            const float4 b  = *(const float4*)&Bt[kk][c0];
            const float4 a0 = *(const float4*)&At[kk][r0];
            const float4 a1 = *(const float4*)&At[kk][r0 + 4];
            const float a[8] = {a0.x, a0.y, a0.z, a0.w, a1.x, a1.y, a1.z, a1.w};
            #pragma unroll
            for (int r = 0; r < 8; ++r) {
                acc[r][0] = fmaf(a[r], b.x, acc[r][0]);
                acc[r][1] = fmaf(a[r], b.y, acc[r][1]);
                acc[r][2] = fmaf(a[r], b.z, acc[r][2]);
                acc[r][3] = fmaf(a[r], b.w, acc[r][3]);
            }
        }
        __syncthreads();
    }
    float4 bias;
    bias.x = b1[c0 + 0] + b2[c0 + 0] + b3[c0 + 0];
    bias.y = b1[c0 + 1] + b2[c0 + 1] + b3[c0 + 1];
    bias.z = b1[c0 + 2] + b2[c0 + 2] + b3[c0 + 2];
    bias.w = b1[c0 + 3] + b2[c0 + 3] + b3[c0 + 3];
    #pragma unroll
    for (int r = 0; r < 8; ++r) {
        const int row = row0 + r0 + r;
        if (row < N) {
            float4 o;
            o.x = fmaxf(acc[r][0] + bias.x, 0.f);
            o.y = fmaxf(acc[r][1] + bias.y, 0.f);
            o.z = fmaxf(acc[r][2] + bias.z, 0.f);
            o.w = fmaxf(acc[r][3] + bias.w, 0.f);
            *(float4*)&H[(size_t)row * FDIM + c0] = o;
        }
    }
}

// ---------------- GEMM2: U_g = Hn @ W_g2 (128->64); also copy into A2_g ----------------
__global__ __launch_bounds__(256) void k_gemm2(
    const float* __restrict__ Hn,
    const float* __restrict__ W1, const float* __restrict__ W2, const float* __restrict__ W3,
    float* __restrict__ U, float* __restrict__ A2, int N) {
    __shared__ float At[16][64];
    __shared__ float Bt[16][64];
    const int t = threadIdx.x;
    const int g = blockIdx.y;
    const int row0 = blockIdx.x * 64;
    const int c0 = (t & 15) * 4;     // 0..60
    const int r0 = (t >> 4) * 4;     // 0..60
    const float* Wg = (g == 0) ? W1 : (g == 1) ? W2 : W3;
    float acc[4][4];
    #pragma unroll
    for (int r = 0; r < 4; ++r)
        #pragma unroll
        for (int c = 0; c < 4; ++c) acc[r][c] = 0.f;

    for (int kb = 0; kb < 8; ++kb) {       // K = 128, tiles of 16
        const int k0 = kb * 16;
        {
            const int kk = t & 15;
            const int rb = t >> 4;          // 0..15
            #pragma unroll
            for (int it = 0; it < 4; ++it) {
                const int r = rb + it * 16;
                const int row = row0 + r;
                At[kk][r] = (row < N) ? Hn[(size_t)row * FDIM + k0 + kk] : 0.f;
            }
        }
        {
            const int n = t & 63;
            const int kkb = t >> 6;         // 0..3
            #pragma unroll
            for (int it = 0; it < 4; ++it) {
                const int kk = kkb + it * 4;
                Bt[kk][n] = Wg[(size_t)(k0 + kk) * ODIM + n];
            }
        }
        __syncthreads();
        #pragma unroll
        for (int kk = 0; kk < 16; ++kk) {
            const float4 b = *(const float4*)&Bt[kk][c0];
            const float4 a = *(const float4*)&At[kk][r0];
            const float av[4] = {a.x, a.y, a.z, a.w};
            #pragma unroll
            for (int r = 0; r < 4; ++r) {
                acc[r][0] = fmaf(av[r], b.x, acc[r][0]);
                acc[r][1] = fmaf(av[r], b.y, acc[r][1]);
                acc[r][2] = fmaf(av[r], b.z, acc[r][2]);
                acc[r][3] = fmaf(av[r], b.w, acc[r][3]);
            }
        }
        __syncthreads();
    }
    float* Ug  = U  + (size_t)g * N * ODIM;
    float* A2g = A2 + (size_t)g * N * ODIM;
    #pragma unroll
    for (int r = 0; r < 4; ++r) {
        const int row = row0 + r0 + r;
        if (row < N) {
            float4 o;
            o.x = acc[r][0]; o.y = acc[r][1]; o.z = acc[r][2]; o.w = acc[r][3];
            *(float4*)&Ug[(size_t)row * ODIM + c0]  = o;
            *(float4*)&A2g[(size_t)row * ODIM + c0] = o;
        }
    }
}

// ---------------- combine: Z = sum_g A2_g * rinv_g + sum_g b_g ----------------
__global__ void k_combine(const float* __restrict__ A2, const float* __restrict__ rinv,
                          const float* __restrict__ b1, const float* __restrict__ b2,
                          const float* __restrict__ b3, float* __restrict__ Z, int N) {
    const size_t n4 = (size_t)N * 16;   // float4 count of N x 64
    const size_t stride = (size_t)gridDim.x * blockDim.x;
    const float4* A4 = (const float4*)A2;
    float4* Z4 = (float4*)Z;
    const size_t gs = (size_t)N * 16;   // float4 stride between graphs
    for (size_t i = (size_t)blockIdx.x * blockDim.x + threadIdx.x; i < n4; i += stride) {
        const int v = (int)(i >> 4);
        const int j = (int)(i & 15);
        const float r0 = rinv[v];
        const float r1 = rinv[N + v];
        const float r2 = rinv[2 * N + v];
        const float4 a0 = A4[i];
        const float4 a1 = A4[i + gs];
        const float4 a2 = A4[i + 2 * gs];
        float4 o;
        o.x = a0.x * r0 + a1.x * r1 + a2.x * r2 + b1[4 * j + 0] + b2[4 * j + 0] + b3[4 * j + 0];
        o.y = a0.y * r0 + a1.y * r1 + a2.y * r2 + b1[4 * j + 1] + b2[4 * j + 1] + b3[4 * j + 1];
        o.z = a0.z * r0 + a1.z * r1 + a2.z * r2 + b1[4 * j + 2] + b2[4 * j + 2] + b3[4 * j + 2];
        o.w = a0.w * r0 + a1.w * r1 + a2.w * r2 + b1[4 * j + 3] + b2[4 * j + 3] + b3[4 * j + 3];
        Z4[i] = o;
    }
}

// ---------------- final: BN3 + sigmoid + row min-max + row L2, in place ----------------
__global__ __launch_bounds__(256) void k_final(float* __restrict__ Z,
                                               const float* __restrict__ scale,
                                               const float* __restrict__ shift, int N) {
    const int wave = threadIdx.x >> 6;
    const int lane = threadIdx.x & 63;
    const int row = blockIdx.x * 4 + wave;
    if (row >= N) return;
    float v = fmaf(Z[(size_t)row * ODIM + lane], scale[lane], shift[lane]);
    float s = 1.0f / (1.0f + expf(-v));
    float mn = s, mx = s;
    #pragma unroll
    for (int off = 32; off; off >>= 1) {
        mn = fminf(mn, __shfl_xor(mn, off, 64));
        mx = fmaxf(mx, __shfl_xor(mx, off, 64));
    }
    const float sc = (s - mn) / (mx - mn);
    float sq = sc * sc;
    #pragma unroll
    for (int off = 32; off; off >>= 1) sq += __shfl_xor(sq, off, 64);
    const float norm = fmaxf(sqrtf(sq), 1e-12f);
    Z[(size_t)row * ODIM + lane] = sc / norm;
}

extern "C" void kernel_launch(void* const* d_in, const int* in_sizes, int n_in,
                              void* d_out, int out_size, void* d_ws, size_t ws_size,
                              hipStream_t stream) {
    const float* x = (const float*)d_in[0];
    const int* src[3] = {(const int*)d_in[1], (const int*)d_in[3], (const int*)d_in[5]};
    const int* dst[3] = {(const int*)d_in[2], (const int*)d_in[4], (const int*)d_in[6]};
    const int E[3] = {in_sizes[1], in_sizes[3], in_sizes[5]};
    const float* W11 = (const float*)d_in[7];  const float* b11 = (const float*)d_in[8];
    const float* W21 = (const float*)d_in[9];  const float* b21 = (const float*)d_in[10];
    const float* W31 = (const float*)d_in[11]; const float* b31 = (const float*)d_in[12];
    const float* W12 = (const float*)d_in[13]; const float* b12 = (const float*)d_in[14];
    const float* W22 = (const float*)d_in[15]; const float* b22 = (const float*)d_in[16];
    const float* W32 = (const float*)d_in[17]; const float* b32 = (const float*)d_in[18];
    const float* g1  = (const float*)d_in[19]; const float* be1 = (const float*)d_in[20];
    const float* g2  = (const float*)d_in[21]; const float* be2 = (const float*)d_in[22];
    const float* g3  = (const float*)d_in[23]; const float* be3 = (const float*)d_in[24];
    const int N = in_sizes[0] / FDIM;
    float* Z = (float*)d_out;

    // workspace layout (floats)
    float* ws   = (float*)d_ws;
    float* P0   = ws;                               // N*128 : xn, then h/hn
    float* P1   = P0 + (size_t)N * FDIM;            // 3*N*128 : AGG, then U|A2
    float* rinv = P1 + (size_t)3 * N * FDIM;        // 3*N
    unsigned* degi = (unsigned*)(rinv + (size_t)3 * N);   // 3*N
    float* partial = (float*)(degi + (size_t)3 * N);      // 65536
    float* s1  = partial + 65536;
    float* sh1 = s1 + 128;
    float* s2  = sh1 + 128;
    float* sh2 = s2 + 128;
    float* s3  = sh2 + 128;
    float* sh3 = s3 + 64;

    hipMemsetAsync(degi, 0, (size_t)3 * N * sizeof(unsigned), stream);
    for (int g = 0; g < 3; ++g)
        k_deg<<<1024, 256, 0, stream>>>(dst[g], E[g], degi + (size_t)g * N);
    k_rinv<<<(3 * N + 255) / 256, 256, 0, stream>>>(degi, rinv, 3 * N);

    // BN1
    k_colstats<128><<<256, 128, 0, stream>>>(x, N, partial);
    k_colstats_fin<128><<<1, 128, 0, stream>>>(partial, 256, N, g1, be1, s1, sh1);
    k_bn_init<<<2048, 256, 0, stream>>>(x, s1, sh1, P0, P1, (size_t)N * 32);

    // layer 1 aggregation + GEMM
    for (int g = 0; g < 3; ++g)
        k_scatter<128><<<4096, 256, 0, stream>>>(src[g], dst[g], P0,
                                                 P1 + (size_t)g * N * FDIM, E[g]);
    k_gemm1<<<(N + 63) / 64, 256, 0, stream>>>(P1, rinv, W11, W21, W31,
                                               b11, b21, b31, P0, N);

    // BN2
    k_colstats<128><<<256, 128, 0, stream>>>(P0, N, partial);
    k_colstats_fin<128><<<1, 128, 0, stream>>>(partial, 256, N, g2, be2, s2, sh2);
    k_bn_apply<<<2048, 256, 0, stream>>>(P0, s2, sh2, (size_t)N * 32);

    // layer 2: GEMM first (linearity), then 64-wide aggregation
    float* U  = P1;
    float* A2 = P1 + (size_t)3 * N * ODIM;
    dim3 grid2((N + 63) / 64, 3);
    k_gemm2<<<grid2, 256, 0, stream>>>(P0, W12, W22, W32, U, A2, N);
    for (int g = 0; g < 3; ++g)
        k_scatter<64><<<4096, 256, 0, stream>>>(src[g], dst[g],
                                                U + (size_t)g * N * ODIM,
                                                A2 + (size_t)g * N * ODIM, E[g]);
    k_combine<<<4096, 256, 0, stream>>>(A2, rinv, b12, b22, b32, Z, N);

    // BN3 + epilogue
    k_colstats<64><<<256, 64, 0, stream>>>(Z, N, partial);
    k_colstats_fin<64><<<1, 64, 0, stream>>>(partial, 256, N, g3, be3, s3, sh3);
    k_final<<<(N + 3) / 4, 256, 0, stream>>>(Z, s3, sh3, N);
}

// Round 2
// 2783.812 us; speedup vs baseline: 2.4122x; 2.4122x over previous
//
#include <hip/hip_runtime.h>
#include <math.h>

constexpr int FDIM = 128;   // IN == HID
constexpr int ODIM = 64;    // NC

// ---------------- column stats (deterministic two-stage) ----------------
template<int C>
__global__ void k_colstats(const float* __restrict__ X, int N, float* __restrict__ partial) {
    const int c = threadIdx.x;          // blockDim.x == C
    const int nb = gridDim.x;
    const int rows_per = (N + nb - 1) / nb;
    const int r0 = blockIdx.x * rows_per;
    const int r1 = min(N, r0 + rows_per);
    float s = 0.f, ss = 0.f;
    for (int r = r0; r < r1; ++r) {
        float v = X[(size_t)r * C + c];
        s += v;
        ss += v * v;
    }
    partial[(size_t)blockIdx.x * (2 * C) + c]     = s;
    partial[(size_t)blockIdx.x * (2 * C) + C + c] = ss;
}

template<int C>
__global__ void k_colstats_fin(const float* __restrict__ partial, int nb, int N,
                               const float* __restrict__ gamma, const float* __restrict__ beta,
                               float* __restrict__ scale, float* __restrict__ shift) {
    const int c = threadIdx.x;          // blockDim.x == C
    float s = 0.f, ss = 0.f;
    for (int b = 0; b < nb; ++b) {
        s  += partial[(size_t)b * (2 * C) + c];
        ss += partial[(size_t)b * (2 * C) + C + c];
    }
    const float mu  = s / (float)N;
    const float var = ss / (float)N - mu * mu;
    const float sc  = gamma[c] * rsqrtf(var + 1e-5f);
    scale[c] = sc;
    shift[c] = beta[c] - mu * sc;
}

// ---------------- degree ----------------
__global__ void k_deg(const int* __restrict__ dst, int E, unsigned* __restrict__ deg) {
    int i = blockIdx.x * blockDim.x + threadIdx.x;
    const int stride = gridDim.x * blockDim.x;
    for (; i < E; i += stride) atomicAdd(&deg[dst[i]], 1u);
}

// ---------------- CSR slot allocation (atomic bump per graph) ----------------
__global__ void k_alloc(const unsigned* __restrict__ deg, unsigned* __restrict__ total,
                        int* __restrict__ off, int* __restrict__ cur,
                        float* __restrict__ rinv, int N) {
    const int i = blockIdx.x * blockDim.x + threadIdx.x;   // over 3N
    if (i >= 3 * N) return;
    const int g = i / N;
    const unsigned d = deg[i];
    const int o = (int)atomicAdd(&total[g], d);
    off[i] = o;
    cur[i] = o;
    rinv[i] = 1.0f / ((float)d + 1.0f);
}

// ---------------- fill CSR neighbor lists ----------------
__global__ void k_fill(const int* __restrict__ src, const int* __restrict__ dst,
                       int* __restrict__ cur, int* __restrict__ nbr, int E) {
    int i = blockIdx.x * blockDim.x + threadIdx.x;
    const int stride = gridDim.x * blockDim.x;
    for (; i < E; i += stride) {
        const int v = dst[i];
        const int p = atomicAdd(&cur[v], 1);
        nbr[p] = src[i];
    }
}

// ---------------- BN1 apply ----------------
__global__ void k_bn_apply_out(const float* __restrict__ x, const float* __restrict__ scale,
                               const float* __restrict__ shift, float* __restrict__ xn, size_t n4) {
    const float4* x4  = (const float4*)x;
    const float4* sc4 = (const float4*)scale;
    const float4* sh4 = (const float4*)shift;
    float4* xn4 = (float4*)xn;
    for (size_t i = (size_t)blockIdx.x * blockDim.x + threadIdx.x; i < n4;
         i += (size_t)gridDim.x * blockDim.x) {
        const int c = (int)(i & 31);
        float4 v = x4[i], sc = sc4[c], sh = sh4[c], o;
        o.x = fmaf(v.x, sc.x, sh.x);
        o.y = fmaf(v.y, sc.y, sh.y);
        o.z = fmaf(v.z, sc.z, sh.z);
        o.w = fmaf(v.w, sc.w, sh.w);
        xn4[i] = o;
    }
}

__global__ void k_bn_apply(float* __restrict__ X, const float* __restrict__ scale,
                           const float* __restrict__ shift, size_t n4) {
    float4* x4 = (float4*)X;
    const float4* sc4 = (const float4*)scale;
    const float4* sh4 = (const float4*)shift;
    for (size_t i = (size_t)blockIdx.x * blockDim.x + threadIdx.x; i < n4;
         i += (size_t)gridDim.x * blockDim.x) {
        const int c = (int)(i & 31);
        float4 v = x4[i], sc = sc4[c], sh = sh4[c];
        v.x = fmaf(v.x, sc.x, sh.x);
        v.y = fmaf(v.y, sc.y, sh.y);
        v.z = fmaf(v.z, sc.z, sh.z);
        v.w = fmaf(v.w, sc.w, sh.w);
        x4[i] = v;
    }
}

// ---------------- gather (128-dim): AGG[v] = rinv[v] * (X[v] + sum_{u in N(v)} X[u]) ----------------
__global__ __launch_bounds__(256) void k_gather128(
    const float* __restrict__ X, const int* __restrict__ nbr,
    const int* __restrict__ off, const int* __restrict__ cend,
    const float* __restrict__ rinv, float* __restrict__ AGG, int N) {
    const int wave = threadIdx.x >> 6;
    const int lane = threadIdx.x & 63;
    const int v = blockIdx.x * 4 + wave;
    if (v >= N) return;
    const int i0 = off[v], i1 = cend[v];
    const int l2 = lane * 2;
    float2 acc = *(const float2*)&X[(size_t)v * FDIM + l2];
    int i = i0;
    for (; i + 4 <= i1; i += 4) {
        const int u0 = nbr[i], u1 = nbr[i + 1], u2 = nbr[i + 2], u3 = nbr[i + 3];
        const float2 a0 = *(const float2*)&X[(size_t)u0 * FDIM + l2];
        const float2 a1 = *(const float2*)&X[(size_t)u1 * FDIM + l2];
        const float2 a2 = *(const float2*)&X[(size_t)u2 * FDIM + l2];
        const float2 a3 = *(const float2*)&X[(size_t)u3 * FDIM + l2];
        acc.x += a0.x + a1.x + a2.x + a3.x;
        acc.y += a0.y + a1.y + a2.y + a3.y;
    }
    for (; i < i1; ++i) {
        const int u = nbr[i];
        const float2 a = *(const float2*)&X[(size_t)u * FDIM + l2];
        acc.x += a.x;
        acc.y += a.y;
    }
    const float r = rinv[v];
    acc.x *= r; acc.y *= r;
    *(float2*)&AGG[(size_t)v * FDIM + l2] = acc;
}

// ---------------- GEMM accumulate: H (+)= A @ W  (A prescaled), 64x128 block ----------------
template<bool INIT, bool RELU>
__global__ __launch_bounds__(256) void k_gemm_acc(
    const float* __restrict__ A, const float* __restrict__ W,
    const float* __restrict__ b1, const float* __restrict__ b2, const float* __restrict__ b3,
    float* __restrict__ H, int N) {
    __shared__ float At[16][64];
    __shared__ float Bt[16][128];
    const int t = threadIdx.x;
    const int row0 = blockIdx.x * 64;
    const int c0 = (t & 31) * 4;     // 0..124
    const int r0 = (t >> 5) * 8;     // 0..56
    float acc[8][4];
    #pragma unroll
    for (int r = 0; r < 8; ++r)
        #pragma unroll
        for (int c = 0; c < 4; ++c) acc[r][c] = 0.f;

    for (int kb = 0; kb < 8; ++kb) {       // K = 128
        const int k0 = kb * 16;
        {
            const int kk = t & 15;
            const int rb = t >> 4;          // 0..15
            #pragma unroll
            for (int it = 0; it < 4; ++it) {
                const int r = rb + it * 16;
                const int row = row0 + r;
                At[kk][r] = (row < N) ? A[(size_t)row * FDIM + k0 + kk] : 0.f;
            }
        }
        {
            const int n = t & 127;
            const int kkb = t >> 7;         // 0..1
            #pragma unroll
            for (int it = 0; it < 8; ++it) {
                const int kk = kkb + it * 2;
                Bt[kk][n] = W[(size_t)(k0 + kk) * 128 + n];
            }
        }
        __syncthreads();
        #pragma unroll
        for (int kk = 0; kk < 16; ++kk) {
            const float4 b  = *(const float4*)&Bt[kk][c0];
            const float4 a0 = *(const float4*)&At[kk][r0];
            const float4 a1 = *(const float4*)&At[kk][r0 + 4];
            const float a[8] = {a0.x, a0.y, a0.z, a0.w, a1.x, a1.y, a1.z, a1.w};
            #pragma unroll
            for (int r = 0; r < 8; ++r) {
                acc[r][0] = fmaf(a[r], b.x, acc[r][0]);
                acc[r][1] = fmaf(a[r], b.y, acc[r][1]);
                acc[r][2] = fmaf(a[r], b.z, acc[r][2]);
                acc[r][3] = fmaf(a[r], b.w, acc[r][3]);
            }
        }
        __syncthreads();
    }
    float4 base;
    if (INIT) {
        base.x = b1[c0 + 0] + b2[c0 + 0] + b3[c0 + 0];
        base.y = b1[c0 + 1] + b2[c0 + 1] + b3[c0 + 1];
        base.z = b1[c0 + 2] + b2[c0 + 2] + b3[c0 + 2];
        base.w = b1[c0 + 3] + b2[c0 + 3] + b3[c0 + 3];
    }
    #pragma unroll
    for (int r = 0; r < 8; ++r) {
        const int row = row0 + r0 + r;
        if (row < N) {
            float4 o;
            float4 prev;
            if (!INIT) prev = *(const float4*)&H[(size_t)row * FDIM + c0];
            o.x = acc[r][0] + (INIT ? base.x : prev.x);
            o.y = acc[r][1] + (INIT ? base.y : prev.y);
            o.z = acc[r][2] + (INIT ? base.z : prev.z);
            o.w = acc[r][3] + (INIT ? base.w : prev.w);
            if (RELU) {
                o.x = fmaxf(o.x, 0.f); o.y = fmaxf(o.y, 0.f);
                o.z = fmaxf(o.z, 0.f); o.w = fmaxf(o.w, 0.f);
            }
            *(float4*)&H[(size_t)row * FDIM + c0] = o;
        }
    }
}

// ---------------- GEMM2: U_g = Hn @ W_g2 (128->64), 3 graphs via blockIdx.y ----------------
__global__ __launch_bounds__(256) void k_gemm2(
    const float* __restrict__ Hn,
    const float* __restrict__ W1, const float* __restrict__ W2, const float* __restrict__ W3,
    float* __restrict__ U, int N) {
    __shared__ float At[16][64];
    __shared__ float Bt[16][64];
    const int t = threadIdx.x;
    const int g = blockIdx.y;
    const int row0 = blockIdx.x * 64;
    const int c0 = (t & 15) * 4;     // 0..60
    const int r0 = (t >> 4) * 4;     // 0..60
    const float* Wg = (g == 0) ? W1 : (g == 1) ? W2 : W3;
    float acc[4][4];
    #pragma unroll
    for (int r = 0; r < 4; ++r)
        #pragma unroll
        for (int c = 0; c < 4; ++c) acc[r][c] = 0.f;

    for (int kb = 0; kb < 8; ++kb) {       // K = 128
        const int k0 = kb * 16;
        {
            const int kk = t & 15;
            const int rb = t >> 4;          // 0..15
            #pragma unroll
            for (int it = 0; it < 4; ++it) {
                const int r = rb + it * 16;
                const int row = row0 + r;
                At[kk][r] = (row < N) ? Hn[(size_t)row * FDIM + k0 + kk] : 0.f;
            }
        }
        {
            const int n = t & 63;
            const int kkb = t >> 6;         // 0..3
            #pragma unroll
            for (int it = 0; it < 4; ++it) {
                const int kk = kkb + it * 4;
                Bt[kk][n] = Wg[(size_t)(k0 + kk) * ODIM + n];
            }
        }
        __syncthreads();
        #pragma unroll
        for (int kk = 0; kk < 16; ++kk) {
            const float4 b = *(const float4*)&Bt[kk][c0];
            const float4 a = *(const float4*)&At[kk][r0];
            const float av[4] = {a.x, a.y, a.z, a.w};
            #pragma unroll
            for (int r = 0; r < 4; ++r) {
                acc[r][0] = fmaf(av[r], b.x, acc[r][0]);
                acc[r][1] = fmaf(av[r], b.y, acc[r][1]);
                acc[r][2] = fmaf(av[r], b.z, acc[r][2]);
                acc[r][3] = fmaf(av[r], b.w, acc[r][3]);
            }
        }
        __syncthreads();
    }
    float* Ug = U + (size_t)g * N * ODIM;
    #pragma unroll
    for (int r = 0; r < 4; ++r) {
        const int row = row0 + r0 + r;
        if (row < N) {
            float4 o;
            o.x = acc[r][0]; o.y = acc[r][1]; o.z = acc[r][2]; o.w = acc[r][3];
            *(float4*)&Ug[(size_t)row * ODIM + c0] = o;
        }
    }
}

// ---------------- layer-2 gather + combine: Z[v] = sum_g rinv_g[v]*(U_g[v]+sum_u U_g[u]) + btot ----------------
__global__ __launch_bounds__(256) void k_gc64(
    const float* __restrict__ U,
    const int* __restrict__ nbr0, const int* __restrict__ nbr1, const int* __restrict__ nbr2,
    const int* __restrict__ off, const int* __restrict__ cend,
    const float* __restrict__ rinv,
    const float* __restrict__ b1, const float* __restrict__ b2, const float* __restrict__ b3,
    float* __restrict__ Z, int N) {
    const int wave = threadIdx.x >> 6;
    const int lane = threadIdx.x & 63;
    const int v = blockIdx.x * 4 + wave;
    if (v >= N) return;
    const size_t gs = (size_t)N * ODIM;
    float z = b1[lane] + b2[lane] + b3[lane];
    #pragma unroll
    for (int g = 0; g < 3; ++g) {
        const float* Ug = U + (size_t)g * gs;
        const int* nb = (g == 0) ? nbr0 : (g == 1) ? nbr1 : nbr2;
        const int i0 = off[g * N + v], i1 = cend[g * N + v];
        float s = Ug[(size_t)v * ODIM + lane];
        int i = i0;
        for (; i + 4 <= i1; i += 4) {
            const int u0 = nb[i], u1 = nb[i + 1], u2 = nb[i + 2], u3 = nb[i + 3];
            s += Ug[(size_t)u0 * ODIM + lane] + Ug[(size_t)u1 * ODIM + lane]
               + Ug[(size_t)u2 * ODIM + lane] + Ug[(size_t)u3 * ODIM + lane];
        }
        for (; i < i1; ++i) s += Ug[(size_t)nb[i] * ODIM + lane];
        z += s * rinv[g * N + v];
    }
    Z[(size_t)v * ODIM + lane] = z;
}

// ---------------- final: BN3 + sigmoid + row min-max + row L2, in place ----------------
__global__ __launch_bounds__(256) void k_final(float* __restrict__ Z,
                                               const float* __restrict__ scale,
                                               const float* __restrict__ shift, int N) {
    const int wave = threadIdx.x >> 6;
    const int lane = threadIdx.x & 63;
    const int row = blockIdx.x * 4 + wave;
    if (row >= N) return;
    float v = fmaf(Z[(size_t)row * ODIM + lane], scale[lane], shift[lane]);
    float s = 1.0f / (1.0f + expf(-v));
    float mn = s, mx = s;
    #pragma unroll
    for (int off = 32; off; off >>= 1) {
        mn = fminf(mn, __shfl_xor(mn, off, 64));
        mx = fmaxf(mx, __shfl_xor(mx, off, 64));
    }
    const float sc = (s - mn) / (mx - mn);
    float sq = sc * sc;
    #pragma unroll
    for (int off = 32; off; off >>= 1) sq += __shfl_xor(sq, off, 64);
    const float norm = fmaxf(sqrtf(sq), 1e-12f);
    Z[(size_t)row * ODIM + lane] = sc / norm;
}

extern "C" void kernel_launch(void* const* d_in, const int* in_sizes, int n_in,
                              void* d_out, int out_size, void* d_ws, size_t ws_size,
                              hipStream_t stream) {
    const float* x = (const float*)d_in[0];
    const int* src[3] = {(const int*)d_in[1], (const int*)d_in[3], (const int*)d_in[5]};
    const int* dst[3] = {(const int*)d_in[2], (const int*)d_in[4], (const int*)d_in[6]};
    const int E[3] = {in_sizes[1], in_sizes[3], in_sizes[5]};
    const float* W11 = (const float*)d_in[7];  const float* b11 = (const float*)d_in[8];
    const float* W21 = (const float*)d_in[9];  const float* b21 = (const float*)d_in[10];
    const float* W31 = (const float*)d_in[11]; const float* b31 = (const float*)d_in[12];
    const float* W12 = (const float*)d_in[13]; const float* b12 = (const float*)d_in[14];
    const float* W22 = (const float*)d_in[15]; const float* b22 = (const float*)d_in[16];
    const float* W32 = (const float*)d_in[17]; const float* b32 = (const float*)d_in[18];
    const float* g1  = (const float*)d_in[19]; const float* be1 = (const float*)d_in[20];
    const float* g2  = (const float*)d_in[21]; const float* be2 = (const float*)d_in[22];
    const float* g3  = (const float*)d_in[23]; const float* be3 = (const float*)d_in[24];
    const int N = in_sizes[0] / FDIM;
    float* Z = (float*)d_out;

    // ---- workspace layout ----
    float* ws  = (float*)d_ws;
    float* B0  = ws;                          // N*128 : xn; later U (3*N*64 spans B0 + half of B1)
    float* B1  = B0 + (size_t)N * FDIM;       // N*128 : AGG scratch
    float* B2  = B1 + (size_t)N * FDIM;       // N*128 : H / Hn
    float* rinv = B2 + (size_t)N * FDIM;      // 3N
    float* partial = rinv + (size_t)3 * N;    // 65536
    float* s1  = partial + 65536;  float* sh1 = s1 + 128;
    float* s2  = sh1 + 128;        float* sh2 = s2 + 128;
    float* s3  = sh2 + 128;        float* sh3 = s3 + 64;
    // int region (16B aligned)
    unsigned* degi  = (unsigned*)(sh3 + 64);              // 3N
    unsigned* total = degi + (size_t)3 * N;               // 4
    int* off  = (int*)(total + 4);                        // 3N
    int* cur  = off + (size_t)3 * N;                      // 3N
    int* nbr  = cur + (size_t)3 * N;                      // E0+E1+E2
    int* nbrg[3];
    nbrg[0] = nbr;
    nbrg[1] = nbrg[0] + E[0];
    nbrg[2] = nbrg[1] + E[1];

    // ---- degrees + CSR build ----
    hipMemsetAsync(degi, 0, ((size_t)3 * N + 4) * sizeof(unsigned), stream);
    for (int g = 0; g < 3; ++g)
        k_deg<<<1024, 256, 0, stream>>>(dst[g], E[g], degi + (size_t)g * N);
    k_alloc<<<(3 * N + 255) / 256, 256, 0, stream>>>(degi, total, off, cur, rinv, N);
    for (int g = 0; g < 3; ++g)
        k_fill<<<2048, 256, 0, stream>>>(src[g], dst[g], cur + (size_t)g * N, nbrg[g], E[g]);

    // ---- BN1 ----
    k_colstats<128><<<256, 128, 0, stream>>>(x, N, partial);
    k_colstats_fin<128><<<1, 128, 0, stream>>>(partial, 256, N, g1, be1, s1, sh1);
    k_bn_apply_out<<<2048, 256, 0, stream>>>(x, s1, sh1, B0, (size_t)N * 32);

    // ---- layer 1: per-graph gather -> accumulate GEMM ----
    const int gblocks = (N + 3) / 4;
    k_gather128<<<gblocks, 256, 0, stream>>>(B0, nbrg[0], off, cur, rinv, B1, N);
    k_gemm_acc<true, false><<<(N + 63) / 64, 256, 0, stream>>>(B1, W11, b11, b21, b31, B2, N);
    k_gather128<<<gblocks, 256, 0, stream>>>(B0, nbrg[1], off + N, cur + N, rinv + N, B1, N);
    k_gemm_acc<false, false><<<(N + 63) / 64, 256, 0, stream>>>(B1, W21, b11, b21, b31, B2, N);
    k_gather128<<<gblocks, 256, 0, stream>>>(B0, nbrg[2], off + 2 * N, cur + 2 * N, rinv + 2 * N, B1, N);
    k_gemm_acc<false, true><<<(N + 63) / 64, 256, 0, stream>>>(B1, W31, b11, b21, b31, B2, N);

    // ---- BN2 (in place on H) ----
    k_colstats<128><<<256, 128, 0, stream>>>(B2, N, partial);
    k_colstats_fin<128><<<1, 128, 0, stream>>>(partial, 256, N, g2, be2, s2, sh2);
    k_bn_apply<<<2048, 256, 0, stream>>>(B2, s2, sh2, (size_t)N * 32);

    // ---- layer 2: GEMM first (linearity), then fused gather+combine ----
    float* U = B0;     // 3*N*64 floats, overlaps dead xn (+ part of B1)
    dim3 grid2((N + 63) / 64, 3);
    k_gemm2<<<grid2, 256, 0, stream>>>(B2, W12, W22, W32, U, N);
    k_gc64<<<gblocks, 256, 0, stream>>>(U, nbrg[0], nbrg[1], nbrg[2], off, cur, rinv,
                                        b12, b22, b32, Z, N);

    // ---- BN3 + epilogue ----
    k_colstats<64><<<256, 64, 0, stream>>>(Z, N, partial);
    k_colstats_fin<64><<<1, 64, 0, stream>>>(partial, 256, N, g3, be3, s3, sh3);
    k_final<<<(N + 3) / 4, 256, 0, stream>>>(Z, s3, sh3, N);
}

// Round 3
// 1203.963 us; speedup vs baseline: 5.5776x; 2.3122x over previous
//
#include <hip/hip_runtime.h>
#include <math.h>

constexpr int FDIM = 128;   // IN == HID
constexpr int ODIM = 64;    // NC

// ---------------- column stats (deterministic two-stage) ----------------
template<int C>
__global__ void k_colstats(const float* __restrict__ X, int N, float* __restrict__ partial) {
    const int c = threadIdx.x;          // blockDim.x == C
    const int nb = gridDim.x;
    const int rows_per = (N + nb - 1) / nb;
    const int r0 = blockIdx.x * rows_per;
    const int r1 = min(N, r0 + rows_per);
    float s = 0.f, ss = 0.f;
    for (int r = r0; r < r1; ++r) {
        float v = X[(size_t)r * C + c];
        s += v;
        ss += v * v;
    }
    partial[(size_t)blockIdx.x * (2 * C) + c]     = s;
    partial[(size_t)blockIdx.x * (2 * C) + C + c] = ss;
}

template<int C>
__global__ void k_colstats_fin(const float* __restrict__ partial, int nb, int N,
                               const float* __restrict__ gamma, const float* __restrict__ beta,
                               float* __restrict__ scale, float* __restrict__ shift) {
    const int c = threadIdx.x;          // blockDim.x == C
    float s = 0.f, ss = 0.f;
    for (int b = 0; b < nb; ++b) {
        s  += partial[(size_t)b * (2 * C) + c];
        ss += partial[(size_t)b * (2 * C) + C + c];
    }
    const float mu  = s / (float)N;
    const float var = ss / (float)N - mu * mu;
    const float sc  = gamma[c] * rsqrtf(var + 1e-5f);
    scale[c] = sc;
    shift[c] = beta[c] - mu * sc;
}

// ---------------- degree ----------------
__global__ void k_deg(const int* __restrict__ dst, int E, unsigned* __restrict__ deg) {
    int i = blockIdx.x * blockDim.x + threadIdx.x;
    const int stride = gridDim.x * blockDim.x;
    for (; i < E; i += stride) atomicAdd(&deg[dst[i]], 1u);
}

// ---------------- deterministic per-graph exclusive scan of degrees ----------------
// one block per graph (blockIdx.x = g), 256 threads
__global__ __launch_bounds__(256) void k_scan(const unsigned* __restrict__ deg,
                                              int* __restrict__ off, int* __restrict__ cur,
                                              float* __restrict__ rinv, int N) {
    const int g = blockIdx.x;
    const unsigned* d = deg + (size_t)g * N;
    int* o = off + (size_t)g * N;
    int* c = cur + (size_t)g * N;
    float* rv = rinv + (size_t)g * N;
    const int t = threadIdx.x;
    const int chunk = (N + 255) / 256;
    const int i0 = min(N, t * chunk);
    const int i1 = min(N, i0 + chunk);
    unsigned s = 0;
    for (int i = i0; i < i1; ++i) s += d[i];
    __shared__ unsigned ps[256];
    ps[t] = s;
    __syncthreads();
    for (int ofs = 1; ofs < 256; ofs <<= 1) {
        const unsigned add = (t >= ofs) ? ps[t - ofs] : 0u;
        __syncthreads();
        ps[t] += add;
        __syncthreads();
    }
    unsigned run = ps[t] - s;   // exclusive prefix for this thread's chunk
    for (int i = i0; i < i1; ++i) {
        const unsigned dd = d[i];
        o[i] = (int)run;
        c[i] = (int)run;
        rv[i] = 1.0f / ((float)dd + 1.0f);
        run += dd;
    }
}

// ---------------- fill CSR neighbor lists ----------------
__global__ void k_fill(const int* __restrict__ src, const int* __restrict__ dst,
                       int* __restrict__ cur, int* __restrict__ nbr, int E) {
    int i = blockIdx.x * blockDim.x + threadIdx.x;
    const int stride = gridDim.x * blockDim.x;
    for (; i < E; i += stride) {
        const int v = dst[i];
        const int p = atomicAdd(&cur[v], 1);
        nbr[p] = src[i];
    }
}

// ---------------- BN1 apply ----------------
__global__ void k_bn_apply_out(const float* __restrict__ x, const float* __restrict__ scale,
                               const float* __restrict__ shift, float* __restrict__ xn, size_t n4) {
    const float4* x4  = (const float4*)x;
    const float4* sc4 = (const float4*)scale;
    const float4* sh4 = (const float4*)shift;
    float4* xn4 = (float4*)xn;
    for (size_t i = (size_t)blockIdx.x * blockDim.x + threadIdx.x; i < n4;
         i += (size_t)gridDim.x * blockDim.x) {
        const int c = (int)(i & 31);
        float4 v = x4[i], sc = sc4[c], sh = sh4[c], o;
        o.x = fmaf(v.x, sc.x, sh.x);
        o.y = fmaf(v.y, sc.y, sh.y);
        o.z = fmaf(v.z, sc.z, sh.z);
        o.w = fmaf(v.w, sc.w, sh.w);
        xn4[i] = o;
    }
}

__global__ void k_bn_apply(float* __restrict__ X, const float* __restrict__ scale,
                           const float* __restrict__ shift, size_t n4) {
    float4* x4 = (float4*)X;
    const float4* sc4 = (const float4*)scale;
    const float4* sh4 = (const float4*)shift;
    for (size_t i = (size_t)blockIdx.x * blockDim.x + threadIdx.x; i < n4;
         i += (size_t)gridDim.x * blockDim.x) {
        const int c = (int)(i & 31);
        float4 v = x4[i], sc = sc4[c], sh = sh4[c];
        v.x = fmaf(v.x, sc.x, sh.x);
        v.y = fmaf(v.y, sc.y, sh.y);
        v.z = fmaf(v.z, sc.z, sh.z);
        v.w = fmaf(v.w, sc.w, sh.w);
        x4[i] = v;
    }
}

// ---------------- gather (128-dim): AGG[v] = rinv[v] * (X[v] + sum_{u in N(v)} X[u]) ----------------
__global__ __launch_bounds__(256) void k_gather128(
    const float* __restrict__ X, const int* __restrict__ nbr,
    const int* __restrict__ off, const int* __restrict__ cend,
    const float* __restrict__ rinv, float* __restrict__ AGG, int N) {
    const int wave = threadIdx.x >> 6;
    const int lane = threadIdx.x & 63;
    const int v = blockIdx.x * 4 + wave;
    if (v >= N) return;
    const int i0 = off[v], i1 = cend[v];
    const int l2 = lane * 2;
    float2 acc = *(const float2*)&X[(size_t)v * FDIM + l2];
    int i = i0;
    for (; i + 4 <= i1; i += 4) {
        const int u0 = nbr[i], u1 = nbr[i + 1], u2 = nbr[i + 2], u3 = nbr[i + 3];
        const float2 a0 = *(const float2*)&X[(size_t)u0 * FDIM + l2];
        const float2 a1 = *(const float2*)&X[(size_t)u1 * FDIM + l2];
        const float2 a2 = *(const float2*)&X[(size_t)u2 * FDIM + l2];
        const float2 a3 = *(const float2*)&X[(size_t)u3 * FDIM + l2];
        acc.x += a0.x + a1.x + a2.x + a3.x;
        acc.y += a0.y + a1.y + a2.y + a3.y;
    }
    for (; i < i1; ++i) {
        const int u = nbr[i];
        const float2 a = *(const float2*)&X[(size_t)u * FDIM + l2];
        acc.x += a.x;
        acc.y += a.y;
    }
    const float r = rinv[v];
    acc.x *= r; acc.y *= r;
    *(float2*)&AGG[(size_t)v * FDIM + l2] = acc;
}

// ---------------- GEMM accumulate: H (+)= A @ W  (A prescaled), 64x128 block ----------------
template<bool INIT, bool RELU>
__global__ __launch_bounds__(256) void k_gemm_acc(
    const float* __restrict__ A, const float* __restrict__ W,
    const float* __restrict__ b1, const float* __restrict__ b2, const float* __restrict__ b3,
    float* __restrict__ H, int N) {
    __shared__ float At[16][64];
    __shared__ float Bt[16][128];
    const int t = threadIdx.x;
    const int row0 = blockIdx.x * 64;
    const int c0 = (t & 31) * 4;     // 0..124
    const int r0 = (t >> 5) * 8;     // 0..56
    float acc[8][4];
    #pragma unroll
    for (int r = 0; r < 8; ++r)
        #pragma unroll
        for (int c = 0; c < 4; ++c) acc[r][c] = 0.f;

    for (int kb = 0; kb < 8; ++kb) {       // K = 128
        const int k0 = kb * 16;
        {
            const int kk = t & 15;
            const int rb = t >> 4;          // 0..15
            #pragma unroll
            for (int it = 0; it < 4; ++it) {
                const int r = rb + it * 16;
                const int row = row0 + r;
                At[kk][r] = (row < N) ? A[(size_t)row * FDIM + k0 + kk] : 0.f;
            }
        }
        {
            const int n = t & 127;
            const int kkb = t >> 7;         // 0..1
            #pragma unroll
            for (int it = 0; it < 8; ++it) {
                const int kk = kkb + it * 2;
                Bt[kk][n] = W[(size_t)(k0 + kk) * 128 + n];
            }
        }
        __syncthreads();
        #pragma unroll
        for (int kk = 0; kk < 16; ++kk) {
            const float4 b  = *(const float4*)&Bt[kk][c0];
            const float4 a0 = *(const float4*)&At[kk][r0];
            const float4 a1 = *(const float4*)&At[kk][r0 + 4];
            const float a[8] = {a0.x, a0.y, a0.z, a0.w, a1.x, a1.y, a1.z, a1.w};
            #pragma unroll
            for (int r = 0; r < 8; ++r) {
                acc[r][0] = fmaf(a[r], b.x, acc[r][0]);
                acc[r][1] = fmaf(a[r], b.y, acc[r][1]);
                acc[r][2] = fmaf(a[r], b.z, acc[r][2]);
                acc[r][3] = fmaf(a[r], b.w, acc[r][3]);
            }
        }
        __syncthreads();
    }
    float4 base;
    if (INIT) {
        base.x = b1[c0 + 0] + b2[c0 + 0] + b3[c0 + 0];
        base.y = b1[c0 + 1] + b2[c0 + 1] + b3[c0 + 1];
        base.z = b1[c0 + 2] + b2[c0 + 2] + b3[c0 + 2];
        base.w = b1[c0 + 3] + b2[c0 + 3] + b3[c0 + 3];
    }
    #pragma unroll
    for (int r = 0; r < 8; ++r) {
        const int row = row0 + r0 + r;
        if (row < N) {
            float4 o;
            float4 prev;
            if (!INIT) prev = *(const float4*)&H[(size_t)row * FDIM + c0];
            o.x = acc[r][0] + (INIT ? base.x : prev.x);
            o.y = acc[r][1] + (INIT ? base.y : prev.y);
            o.z = acc[r][2] + (INIT ? base.z : prev.z);
            o.w = acc[r][3] + (INIT ? base.w : prev.w);
            if (RELU) {
                o.x = fmaxf(o.x, 0.f); o.y = fmaxf(o.y, 0.f);
                o.z = fmaxf(o.z, 0.f); o.w = fmaxf(o.w, 0.f);
            }
            *(float4*)&H[(size_t)row * FDIM + c0] = o;
        }
    }
}

// ---------------- GEMM2: U_g = Hn @ W_g2 (128->64), 3 graphs via blockIdx.y ----------------
__global__ __launch_bounds__(256) void k_gemm2(
    const float* __restrict__ Hn,
    const float* __restrict__ W1, const float* __restrict__ W2, const float* __restrict__ W3,
    float* __restrict__ U, int N) {
    __shared__ float At[16][64];
    __shared__ float Bt[16][64];
    const int t = threadIdx.x;
    const int g = blockIdx.y;
    const int row0 = blockIdx.x * 64;
    const int c0 = (t & 15) * 4;     // 0..60
    const int r0 = (t >> 4) * 4;     // 0..60
    const float* Wg = (g == 0) ? W1 : (g == 1) ? W2 : W3;
    float acc[4][4];
    #pragma unroll
    for (int r = 0; r < 4; ++r)
        #pragma unroll
        for (int c = 0; c < 4; ++c) acc[r][c] = 0.f;

    for (int kb = 0; kb < 8; ++kb) {       // K = 128
        const int k0 = kb * 16;
        {
            const int kk = t & 15;
            const int rb = t >> 4;          // 0..15
            #pragma unroll
            for (int it = 0; it < 4; ++it) {
                const int r = rb + it * 16;
                const int row = row0 + r;
                At[kk][r] = (row < N) ? Hn[(size_t)row * FDIM + k0 + kk] : 0.f;
            }
        }
        {
            const int n = t & 63;
            const int kkb = t >> 6;         // 0..3
            #pragma unroll
            for (int it = 0; it < 4; ++it) {
                const int kk = kkb + it * 4;
                Bt[kk][n] = Wg[(size_t)(k0 + kk) * ODIM + n];
            }
        }
        __syncthreads();
        #pragma unroll
        for (int kk = 0; kk < 16; ++kk) {
            const float4 b = *(const float4*)&Bt[kk][c0];
            const float4 a = *(const float4*)&At[kk][r0];
            const float av[4] = {a.x, a.y, a.z, a.w};
            #pragma unroll
            for (int r = 0; r < 4; ++r) {
                acc[r][0] = fmaf(av[r], b.x, acc[r][0]);
                acc[r][1] = fmaf(av[r], b.y, acc[r][1]);
                acc[r][2] = fmaf(av[r], b.z, acc[r][2]);
                acc[r][3] = fmaf(av[r], b.w, acc[r][3]);
            }
        }
        __syncthreads();
    }
    float* Ug = U + (size_t)g * N * ODIM;
    #pragma unroll
    for (int r = 0; r < 4; ++r) {
        const int row = row0 + r0 + r;
        if (row < N) {
            float4 o;
            o.x = acc[r][0]; o.y = acc[r][1]; o.z = acc[r][2]; o.w = acc[r][3];
            *(float4*)&Ug[(size_t)row * ODIM + c0] = o;
        }
    }
}

// ---------------- layer-2 gather + combine: Z[v] = sum_g rinv_g[v]*(U_g[v]+sum_u U_g[u]) + btot ----------------
__global__ __launch_bounds__(256) void k_gc64(
    const float* __restrict__ U,
    const int* __restrict__ nbr0, const int* __restrict__ nbr1, const int* __restrict__ nbr2,
    const int* __restrict__ off, const int* __restrict__ cend,
    const float* __restrict__ rinv,
    const float* __restrict__ b1, const float* __restrict__ b2, const float* __restrict__ b3,
    float* __restrict__ Z, int N) {
    const int wave = threadIdx.x >> 6;
    const int lane = threadIdx.x & 63;
    const int v = blockIdx.x * 4 + wave;
    if (v >= N) return;
    const size_t gs = (size_t)N * ODIM;
    float z = b1[lane] + b2[lane] + b3[lane];
    #pragma unroll
    for (int g = 0; g < 3; ++g) {
        const float* Ug = U + (size_t)g * gs;
        const int* nb = (g == 0) ? nbr0 : (g == 1) ? nbr1 : nbr2;
        const int i0 = off[g * N + v], i1 = cend[g * N + v];
        float s = Ug[(size_t)v * ODIM + lane];
        int i = i0;
        for (; i + 4 <= i1; i += 4) {
            const int u0 = nb[i], u1 = nb[i + 1], u2 = nb[i + 2], u3 = nb[i + 3];
            s += Ug[(size_t)u0 * ODIM + lane] + Ug[(size_t)u1 * ODIM + lane]
               + Ug[(size_t)u2 * ODIM + lane] + Ug[(size_t)u3 * ODIM + lane];
        }
        for (; i < i1; ++i) s += Ug[(size_t)nb[i] * ODIM + lane];
        z += s * rinv[g * N + v];
    }
    Z[(size_t)v * ODIM + lane] = z;
}

// ---------------- final: BN3 + sigmoid + row min-max + row L2, in place ----------------
__global__ __launch_bounds__(256) void k_final(float* __restrict__ Z,
                                               const float* __restrict__ scale,
                                               const float* __restrict__ shift, int N) {
    const int wave = threadIdx.x >> 6;
    const int lane = threadIdx.x & 63;
    const int row = blockIdx.x * 4 + wave;
    if (row >= N) return;
    float v = fmaf(Z[(size_t)row * ODIM + lane], scale[lane], shift[lane]);
    float s = 1.0f / (1.0f + expf(-v));
    float mn = s, mx = s;
    #pragma unroll
    for (int off = 32; off; off >>= 1) {
        mn = fminf(mn, __shfl_xor(mn, off, 64));
        mx = fmaxf(mx, __shfl_xor(mx, off, 64));
    }
    const float sc = (s - mn) / (mx - mn);
    float sq = sc * sc;
    #pragma unroll
    for (int off = 32; off; off >>= 1) sq += __shfl_xor(sq, off, 64);
    const float norm = fmaxf(sqrtf(sq), 1e-12f);
    Z[(size_t)row * ODIM + lane] = sc / norm;
}

extern "C" void kernel_launch(void* const* d_in, const int* in_sizes, int n_in,
                              void* d_out, int out_size, void* d_ws, size_t ws_size,
                              hipStream_t stream) {
    const float* x = (const float*)d_in[0];
    const int* src[3] = {(const int*)d_in[1], (const int*)d_in[3], (const int*)d_in[5]};
    const int* dst[3] = {(const int*)d_in[2], (const int*)d_in[4], (const int*)d_in[6]};
    const int E[3] = {in_sizes[1], in_sizes[3], in_sizes[5]};
    const float* W11 = (const float*)d_in[7];  const float* b11 = (const float*)d_in[8];
    const float* W21 = (const float*)d_in[9];  const float* b21 = (const float*)d_in[10];
    const float* W31 = (const float*)d_in[11]; const float* b31 = (const float*)d_in[12];
    const float* W12 = (const float*)d_in[13]; const float* b12 = (const float*)d_in[14];
    const float* W22 = (const float*)d_in[15]; const float* b22 = (const float*)d_in[16];
    const float* W32 = (const float*)d_in[17]; const float* b32 = (const float*)d_in[18];
    const float* g1  = (const float*)d_in[19]; const float* be1 = (const float*)d_in[20];
    const float* g2  = (const float*)d_in[21]; const float* be2 = (const float*)d_in[22];
    const float* g3  = (const float*)d_in[23]; const float* be3 = (const float*)d_in[24];
    const int N = in_sizes[0] / FDIM;
    float* Z = (float*)d_out;

    // ---- workspace layout ----
    float* ws  = (float*)d_ws;
    float* B0  = ws;                          // N*128 : xn; later U (3*N*64 spans B0 + half of B1)
    float* B1  = B0 + (size_t)N * FDIM;       // N*128 : AGG scratch
    float* B2  = B1 + (size_t)N * FDIM;       // N*128 : H / Hn
    float* rinv = B2 + (size_t)N * FDIM;      // 3N
    float* partial = rinv + (size_t)3 * N;    // 65536
    float* s1  = partial + 65536;  float* sh1 = s1 + 128;
    float* s2  = sh1 + 128;        float* sh2 = s2 + 128;
    float* s3  = sh2 + 128;        float* sh3 = s3 + 64;
    // int region (16B aligned)
    unsigned* degi  = (unsigned*)(sh3 + 64);              // 3N
    int* off  = (int*)(degi + (size_t)3 * N);             // 3N
    int* cur  = off + (size_t)3 * N;                      // 3N
    int* nbr  = cur + (size_t)3 * N;                      // E0+E1+E2
    int* nbrg[3];
    nbrg[0] = nbr;
    nbrg[1] = nbrg[0] + E[0];
    nbrg[2] = nbrg[1] + E[1];

    // ---- degrees + CSR build (deterministic scan for offsets) ----
    hipMemsetAsync(degi, 0, (size_t)3 * N * sizeof(unsigned), stream);
    for (int g = 0; g < 3; ++g)
        k_deg<<<1024, 256, 0, stream>>>(dst[g], E[g], degi + (size_t)g * N);
    k_scan<<<3, 256, 0, stream>>>(degi, off, cur, rinv, N);
    for (int g = 0; g < 3; ++g)
        k_fill<<<2048, 256, 0, stream>>>(src[g], dst[g], cur + (size_t)g * N, nbrg[g], E[g]);

    // ---- BN1 ----
    k_colstats<128><<<256, 128, 0, stream>>>(x, N, partial);
    k_colstats_fin<128><<<1, 128, 0, stream>>>(partial, 256, N, g1, be1, s1, sh1);
    k_bn_apply_out<<<2048, 256, 0, stream>>>(x, s1, sh1, B0, (size_t)N * 32);

    // ---- layer 1: per-graph gather -> accumulate GEMM ----
    const int gblocks = (N + 3) / 4;
    k_gather128<<<gblocks, 256, 0, stream>>>(B0, nbrg[0], off, cur, rinv, B1, N);
    k_gemm_acc<true, false><<<(N + 63) / 64, 256, 0, stream>>>(B1, W11, b11, b21, b31, B2, N);
    k_gather128<<<gblocks, 256, 0, stream>>>(B0, nbrg[1], off + N, cur + N, rinv + N, B1, N);
    k_gemm_acc<false, false><<<(N + 63) / 64, 256, 0, stream>>>(B1, W21, b11, b21, b31, B2, N);
    k_gather128<<<gblocks, 256, 0, stream>>>(B0, nbrg[2], off + 2 * N, cur + 2 * N, rinv + 2 * N, B1, N);
    k_gemm_acc<false, true><<<(N + 63) / 64, 256, 0, stream>>>(B1, W31, b11, b21, b31, B2, N);

    // ---- BN2 (in place on H) ----
    k_colstats<128><<<256, 128, 0, stream>>>(B2, N, partial);
    k_colstats_fin<128><<<1, 128, 0, stream>>>(partial, 256, N, g2, be2, s2, sh2);
    k_bn_apply<<<2048, 256, 0, stream>>>(B2, s2, sh2, (size_t)N * 32);

    // ---- layer 2: GEMM first (linearity), then fused gather+combine ----
    float* U = B0;     // 3*N*64 floats, overlaps dead xn (+ part of B1)
    dim3 grid2((N + 63) / 64, 3);
    k_gemm2<<<grid2, 256, 0, stream>>>(B2, W12, W22, W32, U, N);
    k_gc64<<<gblocks, 256, 0, stream>>>(U, nbrg[0], nbrg[1], nbrg[2], off, cur, rinv,
                                        b12, b22, b32, Z, N);

    // ---- BN3 + epilogue ----
    k_colstats<64><<<256, 64, 0, stream>>>(Z, N, partial);
    k_colstats_fin<64><<<1, 64, 0, stream>>>(partial, 256, N, g3, be3, s3, sh3);
    k_final<<<(N + 3) / 4, 256, 0, stream>>>(Z, s3, sh3, N);
}

// Round 4
// 1056.729 us; speedup vs baseline: 6.3547x; 1.1393x over previous
//
#include <hip/hip_runtime.h>
#include <math.h>

constexpr int FDIM = 128;   // IN == HID
constexpr int ODIM = 64;    // NC
constexpr int NB   = 256;   // scan blocks per graph

// ---------------- column stats (deterministic two-stage) ----------------
template<int C>
__global__ void k_colstats(const float* __restrict__ X, int N, float* __restrict__ partial) {
    const int c = threadIdx.x;          // blockDim.x == C
    const int nb = gridDim.x;
    const int rows_per = (N + nb - 1) / nb;
    const int r0 = blockIdx.x * rows_per;
    const int r1 = min(N, r0 + rows_per);
    float s = 0.f, ss = 0.f;
    for (int r = r0; r < r1; ++r) {
        float v = X[(size_t)r * C + c];
        s += v;
        ss += v * v;
    }
    partial[(size_t)blockIdx.x * (2 * C) + c]     = s;
    partial[(size_t)blockIdx.x * (2 * C) + C + c] = ss;
}

template<int C>
__global__ void k_colstats_fin(const float* __restrict__ partial, int nb, int N,
                               const float* __restrict__ gamma, const float* __restrict__ beta,
                               float* __restrict__ scale, float* __restrict__ shift) {
    const int c = threadIdx.x;          // blockDim.x == C
    float s = 0.f, ss = 0.f;
    for (int b = 0; b < nb; ++b) {
        s  += partial[(size_t)b * (2 * C) + c];
        ss += partial[(size_t)b * (2 * C) + C + c];
    }
    const float mu  = s / (float)N;
    const float var = ss / (float)N - mu * mu;
    const float sc  = gamma[c] * rsqrtf(var + 1e-5f);
    scale[c] = sc;
    shift[c] = beta[c] - mu * sc;
}

// ---------------- degree ----------------
__global__ void k_deg(const int* __restrict__ dst, int E, unsigned* __restrict__ deg) {
    int i = blockIdx.x * blockDim.x + threadIdx.x;
    const int stride = gridDim.x * blockDim.x;
    for (; i < E; i += stride) atomicAdd(&deg[dst[i]], 1u);
}

// ---------------- parallel deterministic exclusive scan (3 kernels) ----------------
// (a) per-block chunk sums, coalesced
__global__ __launch_bounds__(256) void k_bsum(const unsigned* __restrict__ deg,
                                              unsigned* __restrict__ bsum, int N) {
    const int g = blockIdx.y, b = blockIdx.x, t = threadIdx.x;
    const unsigned* d = deg + (size_t)g * N;
    const int chunk = (N + gridDim.x - 1) / gridDim.x;
    const int i0 = b * chunk, i1 = min(N, i0 + chunk);
    unsigned s = 0;
    for (int i = i0 + t; i < i1; i += 256) s += d[i];
    __shared__ unsigned red[256];
    red[t] = s;
    __syncthreads();
    for (int ofs = 128; ofs; ofs >>= 1) {
        if (t < ofs) red[t] += red[t + ofs];
        __syncthreads();
    }
    if (t == 0) bsum[g * gridDim.x + b] = red[0];
}

// (b) segmented exclusive scan of the 3*NB block sums (one block, 768 threads)
__global__ void k_bscan(unsigned* __restrict__ bsum, int n) {
    const int t = threadIdx.x;
    __shared__ unsigned ps[3 * NB];
    unsigned v = (t < n) ? bsum[t] : 0u;
    ps[t] = v;
    __syncthreads();
    for (int ofs = 1; ofs < NB; ofs <<= 1) {
        const unsigned add = ((t & (NB - 1)) >= ofs) ? ps[t - ofs] : 0u;
        __syncthreads();
        ps[t] += add;
        __syncthreads();
    }
    if (t < n) bsum[t] = ps[t] - v;   // exclusive within each graph segment
}

// (c) per-chunk tiled LDS scan + writeback, coalesced
__global__ __launch_bounds__(256) void k_scan2(const unsigned* __restrict__ deg,
                                               const unsigned* __restrict__ bofs,
                                               int* __restrict__ off, int* __restrict__ cur,
                                               float* __restrict__ rinv, int N) {
    const int g = blockIdx.y, b = blockIdx.x, t = threadIdx.x;
    const unsigned* d = deg + (size_t)g * N;
    int* o = off + (size_t)g * N;
    int* c = cur + (size_t)g * N;
    float* rv = rinv + (size_t)g * N;
    const int chunk = (N + gridDim.x - 1) / gridDim.x;
    const int i0 = b * chunk, i1 = min(N, i0 + chunk);
    unsigned run = bofs[g * gridDim.x + b];
    __shared__ unsigned ps[256];
    for (int base = i0; base < i1; base += 256) {
        const int i = base + t;
        const unsigned v = (i < i1) ? d[i] : 0u;
        ps[t] = v;
        __syncthreads();
        for (int ofs = 1; ofs < 256; ofs <<= 1) {
            const unsigned add = (t >= ofs) ? ps[t - ofs] : 0u;
            __syncthreads();
            ps[t] += add;
            __syncthreads();
        }
        if (i < i1) {
            const unsigned ex = run + ps[t] - v;
            o[i] = (int)ex;
            c[i] = (int)ex;
            rv[i] = 1.0f / ((float)v + 1.0f);
        }
        run += ps[255];
        __syncthreads();
    }
}

// ---------------- fill CSR neighbor lists ----------------
__global__ void k_fill(const int* __restrict__ src, const int* __restrict__ dst,
                       int* __restrict__ cur, int* __restrict__ nbr, int E) {
    int i = blockIdx.x * blockDim.x + threadIdx.x;
    const int stride = gridDim.x * blockDim.x;
    for (; i < E; i += stride) {
        const int v = dst[i];
        const int p = atomicAdd(&cur[v], 1);
        nbr[p] = src[i];
    }
}

// ---------------- BN1 apply ----------------
__global__ void k_bn_apply_out(const float* __restrict__ x, const float* __restrict__ scale,
                               const float* __restrict__ shift, float* __restrict__ xn, size_t n4) {
    const float4* x4  = (const float4*)x;
    const float4* sc4 = (const float4*)scale;
    const float4* sh4 = (const float4*)shift;
    float4* xn4 = (float4*)xn;
    for (size_t i = (size_t)blockIdx.x * blockDim.x + threadIdx.x; i < n4;
         i += (size_t)gridDim.x * blockDim.x) {
        const int c = (int)(i & 31);
        float4 v = x4[i], sc = sc4[c], sh = sh4[c], o;
        o.x = fmaf(v.x, sc.x, sh.x);
        o.y = fmaf(v.y, sc.y, sh.y);
        o.z = fmaf(v.z, sc.z, sh.z);
        o.w = fmaf(v.w, sc.w, sh.w);
        xn4[i] = o;
    }
}

__global__ void k_bn_apply(float* __restrict__ X, const float* __restrict__ scale,
                           const float* __restrict__ shift, size_t n4) {
    float4* x4 = (float4*)X;
    const float4* sc4 = (const float4*)scale;
    const float4* sh4 = (const float4*)shift;
    for (size_t i = (size_t)blockIdx.x * blockDim.x + threadIdx.x; i < n4;
         i += (size_t)gridDim.x * blockDim.x) {
        const int c = (int)(i & 31);
        float4 v = x4[i], sc = sc4[c], sh = sh4[c];
        v.x = fmaf(v.x, sc.x, sh.x);
        v.y = fmaf(v.y, sc.y, sh.y);
        v.z = fmaf(v.z, sc.z, sh.z);
        v.w = fmaf(v.w, sc.w, sh.w);
        x4[i] = v;
    }
}

// ---------------- gather (128-dim): AGG[v] = rinv[v] * (X[v] + sum_{u in N(v)} X[u]) ----------------
__global__ __launch_bounds__(256) void k_gather128(
    const float* __restrict__ X, const int* __restrict__ nbr,
    const int* __restrict__ off, const int* __restrict__ cend,
    const float* __restrict__ rinv, float* __restrict__ AGG, int N) {
    const int wave = threadIdx.x >> 6;
    const int lane = threadIdx.x & 63;
    const int v = blockIdx.x * 4 + wave;
    if (v >= N) return;
    const int i0 = off[v], i1 = cend[v];
    const int l2 = lane * 2;
    float2 acc = *(const float2*)&X[(size_t)v * FDIM + l2];
    int i = i0;
    for (; i + 4 <= i1; i += 4) {
        const int u0 = nbr[i], u1 = nbr[i + 1], u2 = nbr[i + 2], u3 = nbr[i + 3];
        const float2 a0 = *(const float2*)&X[(size_t)u0 * FDIM + l2];
        const float2 a1 = *(const float2*)&X[(size_t)u1 * FDIM + l2];
        const float2 a2 = *(const float2*)&X[(size_t)u2 * FDIM + l2];
        const float2 a3 = *(const float2*)&X[(size_t)u3 * FDIM + l2];
        acc.x += a0.x + a1.x + a2.x + a3.x;
        acc.y += a0.y + a1.y + a2.y + a3.y;
    }
    for (; i < i1; ++i) {
        const int u = nbr[i];
        const float2 a = *(const float2*)&X[(size_t)u * FDIM + l2];
        acc.x += a.x;
        acc.y += a.y;
    }
    const float r = rinv[v];
    acc.x *= r; acc.y *= r;
    *(float2*)&AGG[(size_t)v * FDIM + l2] = acc;
}

// ---------------- GEMM accumulate: H (+)= A @ W  (A prescaled), 64x128 block ----------------
template<bool INIT, bool RELU>
__global__ __launch_bounds__(256) void k_gemm_acc(
    const float* __restrict__ A, const float* __restrict__ W,
    const float* __restrict__ b1, const float* __restrict__ b2, const float* __restrict__ b3,
    float* __restrict__ H, int N) {
    __shared__ float At[16][64];
    __shared__ float Bt[16][128];
    const int t = threadIdx.x;
    const int row0 = blockIdx.x * 64;
    const int c0 = (t & 31) * 4;     // 0..124
    const int r0 = (t >> 5) * 8;     // 0..56
    float acc[8][4];
    #pragma unroll
    for (int r = 0; r < 8; ++r)
        #pragma unroll
        for (int c = 0; c < 4; ++c) acc[r][c] = 0.f;

    for (int kb = 0; kb < 8; ++kb) {       // K = 128
        const int k0 = kb * 16;
        {
            const int kk = t & 15;
            const int rb = t >> 4;          // 0..15
            #pragma unroll
            for (int it = 0; it < 4; ++it) {
                const int r = rb + it * 16;
                const int row = row0 + r;
                At[kk][r] = (row < N) ? A[(size_t)row * FDIM + k0 + kk] : 0.f;
            }
        }
        {
            const int n = t & 127;
            const int kkb = t >> 7;         // 0..1
            #pragma unroll
            for (int it = 0; it < 8; ++it) {
                const int kk = kkb + it * 2;
                Bt[kk][n] = W[(size_t)(k0 + kk) * 128 + n];
            }
        }
        __syncthreads();
        #pragma unroll
        for (int kk = 0; kk < 16; ++kk) {
            const float4 b  = *(const float4*)&Bt[kk][c0];
            const float4 a0 = *(const float4*)&At[kk][r0];
            const float4 a1 = *(const float4*)&At[kk][r0 + 4];
            const float a[8] = {a0.x, a0.y, a0.z, a0.w, a1.x, a1.y, a1.z, a1.w};
            #pragma unroll
            for (int r = 0; r < 8; ++r) {
                acc[r][0] = fmaf(a[r], b.x, acc[r][0]);
                acc[r][1] = fmaf(a[r], b.y, acc[r][1]);
                acc[r][2] = fmaf(a[r], b.z, acc[r][2]);
                acc[r][3] = fmaf(a[r], b.w, acc[r][3]);
            }
        }
        __syncthreads();
    }
    float4 base;
    if (INIT) {
        base.x = b1[c0 + 0] + b2[c0 + 0] + b3[c0 + 0];
        base.y = b1[c0 + 1] + b2[c0 + 1] + b3[c0 + 1];
        base.z = b1[c0 + 2] + b2[c0 + 2] + b3[c0 + 2];
        base.w = b1[c0 + 3] + b2[c0 + 3] + b3[c0 + 3];
    }
    #pragma unroll
    for (int r = 0; r < 8; ++r) {
        const int row = row0 + r0 + r;
        if (row < N) {
            float4 o;
            float4 prev;
            if (!INIT) prev = *(const float4*)&H[(size_t)row * FDIM + c0];
            o.x = acc[r][0] + (INIT ? base.x : prev.x);
            o.y = acc[r][1] + (INIT ? base.y : prev.y);
            o.z = acc[r][2] + (INIT ? base.z : prev.z);
            o.w = acc[r][3] + (INIT ? base.w : prev.w);
            if (RELU) {
                o.x = fmaxf(o.x, 0.f); o.y = fmaxf(o.y, 0.f);
                o.z = fmaxf(o.z, 0.f); o.w = fmaxf(o.w, 0.f);
            }
            *(float4*)&H[(size_t)row * FDIM + c0] = o;
        }
    }
}

// ---------------- GEMM2: U_g = Hn @ W_g2 (128->64), 3 graphs via blockIdx.y ----------------
__global__ __launch_bounds__(256) void k_gemm2(
    const float* __restrict__ Hn,
    const float* __restrict__ W1, const float* __restrict__ W2, const float* __restrict__ W3,
    float* __restrict__ U, int N) {
    __shared__ float At[16][64];
    __shared__ float Bt[16][64];
    const int t = threadIdx.x;
    const int g = blockIdx.y;
    const int row0 = blockIdx.x * 64;
    const int c0 = (t & 15) * 4;     // 0..60
    const int r0 = (t >> 4) * 4;     // 0..60
    const float* Wg = (g == 0) ? W1 : (g == 1) ? W2 : W3;
    float acc[4][4];
    #pragma unroll
    for (int r = 0; r < 4; ++r)
        #pragma unroll
        for (int c = 0; c < 4; ++c) acc[r][c] = 0.f;

    for (int kb = 0; kb < 8; ++kb) {       // K = 128
        const int k0 = kb * 16;
        {
            const int kk = t & 15;
            const int rb = t >> 4;          // 0..15
            #pragma unroll
            for (int it = 0; it < 4; ++it) {
                const int r = rb + it * 16;
                const int row = row0 + r;
                At[kk][r] = (row < N) ? Hn[(size_t)row * FDIM + k0 + kk] : 0.f;
            }
        }
        {
            const int n = t & 63;
            const int kkb = t >> 6;         // 0..3
            #pragma unroll
            for (int it = 0; it < 4; ++it) {
                const int kk = kkb + it * 4;
                Bt[kk][n] = Wg[(size_t)(k0 + kk) * ODIM + n];
            }
        }
        __syncthreads();
        #pragma unroll
        for (int kk = 0; kk < 16; ++kk) {
            const float4 b = *(const float4*)&Bt[kk][c0];
            const float4 a = *(const float4*)&At[kk][r0];
            const float av[4] = {a.x, a.y, a.z, a.w};
            #pragma unroll
            for (int r = 0; r < 4; ++r) {
                acc[r][0] = fmaf(av[r], b.x, acc[r][0]);
                acc[r][1] = fmaf(av[r], b.y, acc[r][1]);
                acc[r][2] = fmaf(av[r], b.z, acc[r][2]);
                acc[r][3] = fmaf(av[r], b.w, acc[r][3]);
            }
        }
        __syncthreads();
    }
    float* Ug = U + (size_t)g * N * ODIM;
    #pragma unroll
    for (int r = 0; r < 4; ++r) {
        const int row = row0 + r0 + r;
        if (row < N) {
            float4 o;
            o.x = acc[r][0]; o.y = acc[r][1]; o.z = acc[r][2]; o.w = acc[r][3];
            *(float4*)&Ug[(size_t)row * ODIM + c0] = o;
        }
    }
}

// ---------------- layer-2 gather + combine: Z[v] = sum_g rinv_g[v]*(U_g[v]+sum_u U_g[u]) + btot ----------------
__global__ __launch_bounds__(256) void k_gc64(
    const float* __restrict__ U,
    const int* __restrict__ nbr0, const int* __restrict__ nbr1, const int* __restrict__ nbr2,
    const int* __restrict__ off, const int* __restrict__ cend,
    const float* __restrict__ rinv,
    const float* __restrict__ b1, const float* __restrict__ b2, const float* __restrict__ b3,
    float* __restrict__ Z, int N) {
    const int wave = threadIdx.x >> 6;
    const int lane = threadIdx.x & 63;
    const int v = blockIdx.x * 4 + wave;
    if (v >= N) return;
    const size_t gs = (size_t)N * ODIM;
    float z = b1[lane] + b2[lane] + b3[lane];
    #pragma unroll
    for (int g = 0; g < 3; ++g) {
        const float* Ug = U + (size_t)g * gs;
        const int* nb = (g == 0) ? nbr0 : (g == 1) ? nbr1 : nbr2;
        const int i0 = off[g * N + v], i1 = cend[g * N + v];
        float s = Ug[(size_t)v * ODIM + lane];
        int i = i0;
        for (; i + 4 <= i1; i += 4) {
            const int u0 = nb[i], u1 = nb[i + 1], u2 = nb[i + 2], u3 = nb[i + 3];
            s += Ug[(size_t)u0 * ODIM + lane] + Ug[(size_t)u1 * ODIM + lane]
               + Ug[(size_t)u2 * ODIM + lane] + Ug[(size_t)u3 * ODIM + lane];
        }
        for (; i < i1; ++i) s += Ug[(size_t)nb[i] * ODIM + lane];
        z += s * rinv[g * N + v];
    }
    Z[(size_t)v * ODIM + lane] = z;
}

// ---------------- final: BN3 + sigmoid + row min-max + row L2, in place ----------------
__global__ __launch_bounds__(256) void k_final(float* __restrict__ Z,
                                               const float* __restrict__ scale,
                                               const float* __restrict__ shift, int N) {
    const int wave = threadIdx.x >> 6;
    const int lane = threadIdx.x & 63;
    const int row = blockIdx.x * 4 + wave;
    if (row >= N) return;
    float v = fmaf(Z[(size_t)row * ODIM + lane], scale[lane], shift[lane]);
    float s = 1.0f / (1.0f + expf(-v));
    float mn = s, mx = s;
    #pragma unroll
    for (int off = 32; off; off >>= 1) {
        mn = fminf(mn, __shfl_xor(mn, off, 64));
        mx = fmaxf(mx, __shfl_xor(mx, off, 64));
    }
    const float sc = (s - mn) / (mx - mn);
    float sq = sc * sc;
    #pragma unroll
    for (int off = 32; off; off >>= 1) sq += __shfl_xor(sq, off, 64);
    const float norm = fmaxf(sqrtf(sq), 1e-12f);
    Z[(size_t)row * ODIM + lane] = sc / norm;
}

extern "C" void kernel_launch(void* const* d_in, const int* in_sizes, int n_in,
                              void* d_out, int out_size, void* d_ws, size_t ws_size,
                              hipStream_t stream) {
    const float* x = (const float*)d_in[0];
    const int* src[3] = {(const int*)d_in[1], (const int*)d_in[3], (const int*)d_in[5]};
    const int* dst[3] = {(const int*)d_in[2], (const int*)d_in[4], (const int*)d_in[6]};
    const int E[3] = {in_sizes[1], in_sizes[3], in_sizes[5]};
    const float* W11 = (const float*)d_in[7];  const float* b11 = (const float*)d_in[8];
    const float* W21 = (const float*)d_in[9];  const float* b21 = (const float*)d_in[10];
    const float* W31 = (const float*)d_in[11]; const float* b31 = (const float*)d_in[12];
    const float* W12 = (const float*)d_in[13]; const float* b12 = (const float*)d_in[14];
    const float* W22 = (const float*)d_in[15]; const float* b22 = (const float*)d_in[16];
    const float* W32 = (const float*)d_in[17]; const float* b32 = (const float*)d_in[18];
    const float* g1  = (const float*)d_in[19]; const float* be1 = (const float*)d_in[20];
    const float* g2  = (const float*)d_in[21]; const float* be2 = (const float*)d_in[22];
    const float* g3  = (const float*)d_in[23]; const float* be3 = (const float*)d_in[24];
    const int N = in_sizes[0] / FDIM;
    float* Z = (float*)d_out;

    // ---- workspace layout ----
    float* ws  = (float*)d_ws;
    float* B0  = ws;                          // N*128 : xn; later U (3*N*64 spans B0 + half of B1)
    float* B1  = B0 + (size_t)N * FDIM;       // N*128 : AGG scratch
    float* B2  = B1 + (size_t)N * FDIM;       // N*128 : H / Hn
    float* rinv = B2 + (size_t)N * FDIM;      // 3N
    float* partial = rinv + (size_t)3 * N;    // 65536
    float* s1  = partial + 65536;  float* sh1 = s1 + 128;
    float* s2  = sh1 + 128;        float* sh2 = s2 + 128;
    float* s3  = sh2 + 128;        float* sh3 = s3 + 64;
    // int region (16B aligned)
    unsigned* degi  = (unsigned*)(sh3 + 64);              // 3N
    unsigned* bsum  = degi + (size_t)3 * N;               // 3*NB
    int* off  = (int*)(bsum + (size_t)3 * NB);            // 3N
    int* cur  = off + (size_t)3 * N;                      // 3N
    int* nbr  = cur + (size_t)3 * N;                      // E0+E1+E2
    int* nbrg[3];
    nbrg[0] = nbr;
    nbrg[1] = nbrg[0] + E[0];
    nbrg[2] = nbrg[1] + E[1];

    // ---- degrees + CSR build (deterministic parallel scan for offsets) ----
    hipMemsetAsync(degi, 0, (size_t)3 * N * sizeof(unsigned), stream);
    for (int g = 0; g < 3; ++g)
        k_deg<<<1024, 256, 0, stream>>>(dst[g], E[g], degi + (size_t)g * N);
    k_bsum<<<dim3(NB, 3), 256, 0, stream>>>(degi, bsum, N);
    k_bscan<<<1, 3 * NB, 0, stream>>>(bsum, 3 * NB);
    k_scan2<<<dim3(NB, 3), 256, 0, stream>>>(degi, bsum, off, cur, rinv, N);
    for (int g = 0; g < 3; ++g)
        k_fill<<<2048, 256, 0, stream>>>(src[g], dst[g], cur + (size_t)g * N, nbrg[g], E[g]);

    // ---- BN1 ----
    k_colstats<128><<<256, 128, 0, stream>>>(x, N, partial);
    k_colstats_fin<128><<<1, 128, 0, stream>>>(partial, 256, N, g1, be1, s1, sh1);
    k_bn_apply_out<<<2048, 256, 0, stream>>>(x, s1, sh1, B0, (size_t)N * 32);

    // ---- layer 1: per-graph gather -> accumulate GEMM ----
    const int gblocks = (N + 3) / 4;
    k_gather128<<<gblocks, 256, 0, stream>>>(B0, nbrg[0], off, cur, rinv, B1, N);
    k_gemm_acc<true, false><<<(N + 63) / 64, 256, 0, stream>>>(B1, W11, b11, b21, b31, B2, N);
    k_gather128<<<gblocks, 256, 0, stream>>>(B0, nbrg[1], off + N, cur + N, rinv + N, B1, N);
    k_gemm_acc<false, false><<<(N + 63) / 64, 256, 0, stream>>>(B1, W21, b11, b21, b31, B2, N);
    k_gather128<<<gblocks, 256, 0, stream>>>(B0, nbrg[2], off + 2 * N, cur + 2 * N, rinv + 2 * N, B1, N);
    k_gemm_acc<false, true><<<(N + 63) / 64, 256, 0, stream>>>(B1, W31, b11, b21, b31, B2, N);

    // ---- BN2 (in place on H) ----
    k_colstats<128><<<256, 128, 0, stream>>>(B2, N, partial);
    k_colstats_fin<128><<<1, 128, 0, stream>>>(partial, 256, N, g2, be2, s2, sh2);
    k_bn_apply<<<2048, 256, 0, stream>>>(B2, s2, sh2, (size_t)N * 32);

    // ---- layer 2: GEMM first (linearity), then fused gather+combine ----
    float* U = B0;     // 3*N*64 floats, overlaps dead xn (+ part of B1)
    dim3 grid2((N + 63) / 64, 3);
    k_gemm2<<<grid2, 256, 0, stream>>>(B2, W12, W22, W32, U, N);
    k_gc64<<<gblocks, 256, 0, stream>>>(U, nbrg[0], nbrg[1], nbrg[2], off, cur, rinv,
                                        b12, b22, b32, Z, N);

    // ---- BN3 + epilogue ----
    k_colstats<64><<<256, 64, 0, stream>>>(Z, N, partial);
    k_colstats_fin<64><<<1, 64, 0, stream>>>(partial, 256, N, g3, be3, s3, sh3);
    k_final<<<(N + 3) / 4, 256, 0, stream>>>(Z, s3, sh3, N);
}